// Round 6
// baseline (197.147 us; speedup 1.0000x reference)
//
#include <hip/hip_runtime.h>
#include <math.h>

#define BB 4
#define CC 1024
#define TT 1024
#define HH 16
#define HDD 64

typedef float floatx4 __attribute__((ext_vector_type(4)));
typedef __bf16 bf16x8 __attribute__((ext_vector_type(8)));
typedef __bf16 bf16x4 __attribute__((ext_vector_type(4)));

__device__ __forceinline__ void gld_lds16(const __bf16* g, __bf16* l) {
    __builtin_amdgcn_global_load_lds(
        (__attribute__((address_space(1))) void*)(g),
        (__attribute__((address_space(3))) void*)(l), 16, 0, 0);
}

// Pipeline sync: counted vmcnt + raw barrier, sched_barrier(0)-bracketed so
// (a) prior phase's ds_reads/MFMAs cannot sink below the barrier and
// (b) next phase's ds_reads cannot hoist above it (rule #18: s_barrier is
// NOT a compiler memory fence; inline-asm waitcnt doesn't order reg-only MFMA).
#define PIPE_SYNC(VM)                                               \
    do {                                                            \
        __builtin_amdgcn_sched_barrier(0);                          \
        asm volatile("s_waitcnt vmcnt(" #VM ")" ::: "memory");      \
        __builtin_amdgcn_s_barrier();                               \
        __builtin_amdgcn_sched_barrier(0);                          \
    } while (0)

// ---------------------------------------------------------------------------
// Fused prep: z<8 -> transpose (b,C,T) f32 -> (b,T,C) bf16 for x,c;
//             z==8 -> weight f32->bf16 conversion (coalesced).
// ---------------------------------------------------------------------------
__global__ __launch_bounds__(256) void prep_kernel(
    const float* __restrict__ x, const float* __restrict__ c,
    __bf16* __restrict__ xT, __bf16* __restrict__ cT,
    const float* __restrict__ Wq, const float* __restrict__ Wk,
    const float* __restrict__ Wv, const float* __restrict__ Wo,
    __bf16* __restrict__ Wqb, __bf16* __restrict__ Wkb,
    __bf16* __restrict__ Wvb, __bf16* __restrict__ Wob) {
    __shared__ float tile[64][65];
    int tid = threadIdx.x;
    int z = blockIdx.z;
    if (z == 8) {
        const float* srcs[4] = {Wq, Wk, Wv, Wo};
        __bf16* dsts[4] = {Wqb, Wkb, Wvb, Wob};
        int bid = blockIdx.y * 16 + blockIdx.x;   // 0..255
        int mi = bid >> 6;
        const float* s = srcs[mi];
        __bf16* d = dsts[mi];
        int base = (bid & 63) * 16384;
#pragma unroll
        for (int u = 0; u < 16; ++u) {
            int idx = base + u * 1024 + tid * 4;
            float4 v4 = *(const float4*)(s + idx);
            bf16x4 o;
            o[0] = (__bf16)v4.x; o[1] = (__bf16)v4.y;
            o[2] = (__bf16)v4.z; o[3] = (__bf16)v4.w;
            *(bf16x4*)(d + idx) = o;
        }
        return;
    }
    const float* src = (z < 4) ? x : c;
    __bf16* dst = (z < 4) ? xT : cT;
    int b = z & 3;
    int t0 = blockIdx.x * 64, c0 = blockIdx.y * 64;
    int r = tid >> 2, s16 = (tid & 3) * 16;
    const float* sp = src + (size_t)b * CC * TT + (size_t)(c0 + r) * TT + t0 + s16;
    float4 a0 = *(const float4*)(sp + 0);
    float4 a1 = *(const float4*)(sp + 4);
    float4 a2 = *(const float4*)(sp + 8);
    float4 a3 = *(const float4*)(sp + 12);
    float* tr = &tile[r][s16];
    tr[0] = a0.x; tr[1] = a0.y; tr[2]  = a0.z; tr[3]  = a0.w;
    tr[4] = a1.x; tr[5] = a1.y; tr[6]  = a1.z; tr[7]  = a1.w;
    tr[8] = a2.x; tr[9] = a2.y; tr[10] = a2.z; tr[11] = a2.w;
    tr[12] = a3.x; tr[13] = a3.y; tr[14] = a3.z; tr[15] = a3.w;
    __syncthreads();
    bf16x8 p0, p1;
#pragma unroll
    for (int j = 0; j < 8; ++j) {
        p0[j] = (__bf16)tile[s16 + j][r];
        p1[j] = (__bf16)tile[s16 + 8 + j][r];
    }
    __bf16* dp = dst + (size_t)b * TT * CC + (size_t)(t0 + r) * CC + c0 + s16;
    *(bf16x8*)(dp) = p0;
    *(bf16x8*)(dp + 8) = p1;
}

// ---------------------------------------------------------------------------
// 128xBN tile (BN=128 or 64), BK=32, THREE-buffer counted-vmcnt pipeline,
// B^T input. Stage is issued 2 K-tiles ahead; counted vmcnt + raw barrier
// (no vmcnt(0) drain in the main loop — T4).
// Buffer i at elem offset i*BSTRIDE: A [128][32] at +0, B [BN][32] at +4096.
//
// LDS swizzle (T2, fixed this round): store-side pre-swizzles the GLOBAL
// column group with row bits 1-2 (g_glob = (l&3) ^ ((l>>3)&3)); read-side
// uses v8 = (lq ^ ((lm>>1)&3))*8. Old scheme XORed row bits 0-1; row bit 0
// already selects the bank half, so even-lm lanes hit only 2 column slots ->
// 4-way conflict (measured: SQ_LDS_BANK_CONFLICT 3.34M/dispatch, ~13% of
// qkv cycles). New scheme: lanes lm and lm+8 share a slot -> 2-way = free.
// NO setprio here (measured R3: m190 lockstep-GEMM regression).
// EPI 0: out bf16 (b,C,T) + bias | EPI 1: rope -> (h,t,d) | EPI 2: f32 + bias
// ---------------------------------------------------------------------------
template <int EPI, int BN, typename OutT>
__device__ __forceinline__ void gemm_bt32(
    __bf16* smem, const __bf16* __restrict__ A, const __bf16* __restrict__ Bt,
    const float* __restrict__ bias, OutT* __restrict__ out, float qs,
    int m0, int n0) {
    constexpr int BSTRIDE = 4096 + BN * 32;   // elems per pipeline buffer
    constexpr int NJ = BN / 32;               // B-fragments per wave (4 or 2)
    const int tid = threadIdx.x, l = tid & 63, w = tid >> 6;
    const int wm = (w >> 1) * 64, wn = (w & 1) * (BN / 2);
    const int lm = l & 15, lq = l >> 4;
    const int v8 = (lq ^ ((lm >> 1) & 3)) * 8;   // swizzled col-group (read)
    const int srow = l >> 2;                     // 0..15 staging row
    const int gcg = ((l & 3) ^ ((l >> 3) & 3)) * 8;  // global-side swizzle

    // wave w stages 32 rows of A (2 chunks) and BN/4 rows of B (2 or 1 chunk)
    const __bf16* ga = A + (size_t)(m0 + w * 32 + srow) * 1024 + gcg;
    const __bf16* gb = Bt + (size_t)(n0 + w * (BN / 4) + srow) * 1024 + gcg;
    __bf16* adst = smem + w * 1024;                 // + buffer offset
    __bf16* bdst = smem + 4096 + w * (BN / 4) * 32; // + buffer offset

#define GSTAGE(BUFOFF)                                          \
    do {                                                        \
        gld_lds16(ga, adst + (BUFOFF));                         \
        gld_lds16(ga + 16 * 1024, adst + (BUFOFF) + 512);       \
        gld_lds16(gb, bdst + (BUFOFF));                         \
        if constexpr (BN == 128)                                \
            gld_lds16(gb + 16 * 1024, bdst + (BUFOFF) + 512);   \
        ga += 32;                                               \
        gb += 32;                                               \
    } while (0)

#define GCOMP(BUFOFF)                                                          \
    do {                                                                       \
        bf16x8 af[4], bfr[NJ];                                                 \
        _Pragma("unroll") for (int i = 0; i < 4; ++i)                          \
            af[i] = *(bf16x8*)&smem[(BUFOFF) + (wm + i * 16 + lm) * 32 + v8];  \
        _Pragma("unroll") for (int j = 0; j < NJ; ++j)                         \
            bfr[j] = *(bf16x8*)&smem[(BUFOFF) + 4096 + (wn + j * 16 + lm) * 32 + v8]; \
        _Pragma("unroll") for (int i = 0; i < 4; ++i)                          \
            _Pragma("unroll") for (int j = 0; j < NJ; ++j)                     \
                acc[i][j] = __builtin_amdgcn_mfma_f32_16x16x32_bf16(af[i], bfr[j], acc[i][j], 0, 0, 0); \
    } while (0)

#define GITER(CUR, NXT)                                      \
    do {                                                     \
        if constexpr (BN == 128) PIPE_SYNC(4); else PIPE_SYNC(3); \
        GSTAGE(NXT);                                         \
        GCOMP(CUR);                                          \
    } while (0)

    floatx4 acc[4][NJ];
#pragma unroll
    for (int i = 0; i < 4; ++i)
#pragma unroll
        for (int j = 0; j < NJ; ++j) acc[i][j] = (floatx4){0.f, 0.f, 0.f, 0.f};

    GSTAGE(0);            // stage kt=0 -> buf0
    GSTAGE(BSTRIDE);      // stage kt=1 -> buf1
#pragma unroll 1
    for (int kt = 0; kt < 30; kt += 3) {
        GITER(0,           2 * BSTRIDE);  // compute kt,   stage kt+2 -> buf2
        GITER(BSTRIDE,     0);            // compute kt+1, stage kt+3 -> buf0
        GITER(2 * BSTRIDE, BSTRIDE);      // compute kt+2, stage kt+4 -> buf1
    }
    // kt=30: buf0, no further stage (only kt=31's loads may remain)
    if constexpr (BN == 128) PIPE_SYNC(4); else PIPE_SYNC(3);
    GCOMP(0);
    // kt=31: buf1, drain
    PIPE_SYNC(0);
    GCOMP(BSTRIDE);
#undef GSTAGE
#undef GCOMP
#undef GITER

    if constexpr (EPI == 1) {
        // ---- bias + RoPE in registers, write (h,t,d) via LDS bounce ----
        float b4[4][4];
#pragma unroll
        for (int i = 0; i < 4; ++i)
#pragma unroll
            for (int r = 0; r < 4; ++r) b4[i][r] = bias[m0 + wm + i * 16 + lq * 4 + r];
#pragma unroll
        for (int r = 0; r < 4; ++r) {
            // theta = 10000^(-(lq*4+r)/16)
            float theta = __expf(-0.57564627f * (float)(lq * 4 + r));
#pragma unroll
            for (int j = 0; j < 4; ++j) {
                float ang = (float)(n0 + wn + j * 16 + lm) * theta;
                float cs = __cosf(ang), sn = __sinf(ang);
                float a0 = acc[0][j][r] + b4[0][r];
                float a1 = acc[1][j][r] + b4[1][r];
                acc[0][j][r] = (a0 * cs - a1 * sn) * qs;
                acc[1][j][r] = (a1 * cs + a0 * sn) * qs;
                acc[2][j][r] = (acc[2][j][r] + b4[2][r]) * qs;
                acc[3][j][r] = (acc[3][j][r] + b4[3][r]) * qs;
            }
        }
        __syncthreads();  // full drain+fence; reuse smem as o_lds [256][72]
        const int hl = wm >> 6;
#pragma unroll
        for (int j = 0; j < 4; ++j) {
            int row = hl * 128 + wn + j * 16 + lm;
#pragma unroll
            for (int i = 0; i < 4; ++i) {
                bf16x4 pk;
#pragma unroll
                for (int r = 0; r < 4; ++r) pk[r] = (__bf16)acc[i][j][r];
                *(bf16x4*)&smem[row * 72 + i * 16 + lq * 4] = pk;
            }
        }
        __syncthreads();
        const size_t hbase = (size_t)(m0 >> 6) * (TT * 64);
#pragma unroll
        for (int it = 0; it < 8; ++it) {
            int chunk = tid + 256 * it;
            int row = chunk >> 3, off = (chunk & 7) * 8;  // row 0..255
            int hh = row >> 7, t = n0 + (row & 127);
            *(bf16x8*)&out[hbase + (size_t)hh * (TT * 64) + (size_t)t * 64 + off] =
                *(bf16x8*)&smem[row * 72 + off];
        }
    } else {
#pragma unroll
        for (int i = 0; i < 4; ++i) {
            int mbase = m0 + wm + i * 16 + lq * 4;
#pragma unroll
            for (int r = 0; r < 4; ++r) {
                float bv = bias[mbase + r];
                size_t rowoff = (size_t)(mbase + r) * 1024 + n0 + wn + lm;
#pragma unroll
                for (int j = 0; j < NJ; ++j)
                    out[rowoff + j * 16] = (OutT)(acc[i][j][r] + bv);
            }
        }
    }
}

// T1: XCD-aware chunked swizzle. nwg is a multiple of 8 (768 / 512) ->
// bijective. XCD k gets a contiguous chunk of nwg/8 tiles, so shared A/B
// panels stay in one XCD's L2 (measured R3/R4: FETCH 37.0 -> 32.0 MB).
__global__ __launch_bounds__(256) void gemm_qkv_kernel(
    const __bf16* __restrict__ Wqb, const __bf16* __restrict__ Wkb, const __bf16* __restrict__ Wvb,
    const __bf16* __restrict__ xT, const __bf16* __restrict__ cT,
    const float* __restrict__ bq, const float* __restrict__ bk, const float* __restrict__ bv,
    __bf16* __restrict__ qhb, __bf16* __restrict__ khb, __bf16* __restrict__ vb) {
    __shared__ __bf16 smem[24576];  // 48 KB: 3 pipeline buffers; epilogue reuse
    int lin = blockIdx.x + 8 * blockIdx.y + 64 * blockIdx.z;   // 0..767
    int swz = (lin & 7) * 96 + (lin >> 3);                     // XCD-chunked
    int z = swz >> 6, rem = swz & 63;
    int m0 = (rem >> 3) * 128, n0 = (rem & 7) * 128;
    int which = z >> 2, b = z & 3;
    if (which == 0) {
        gemm_bt32<1, 128, __bf16>(smem, Wqb, xT + (size_t)b * TT * CC, bq,
                                  qhb + (size_t)b * HH * TT * 64, 0.18033688f, m0, n0);
    } else if (which == 1) {
        gemm_bt32<1, 128, __bf16>(smem, Wkb, cT + (size_t)b * TT * CC, bk,
                                  khb + (size_t)b * HH * TT * 64, 1.0f, m0, n0);
    } else {
        gemm_bt32<0, 128, __bf16>(smem, Wvb, cT + (size_t)b * TT * CC, bv,
                                  vb + (size_t)b * CC * TT, 1.0f, m0, n0);
    }
}

// 128x64 tiles: grid 512 = 2 blocks/CU (was 256 = 1/CU with all pipeline
// stalls exposed). LDS 36 KB.
__global__ __launch_bounds__(256) void gemm_out_kernel(
    const __bf16* __restrict__ Wob, const __bf16* __restrict__ attT,
    const float* __restrict__ bo, float* __restrict__ out) {
    __shared__ __bf16 smem[18432];  // 3 x 6144-elem buffers
    int lin = blockIdx.x + 16 * blockIdx.y + 128 * blockIdx.z;  // 0..511
    int swz = (lin & 7) * 64 + (lin >> 3);                      // XCD-chunked
    int z = swz >> 7, rem = swz & 127;
    int m0 = (rem >> 4) * 128, n0 = (rem & 15) * 64;
    gemm_bt32<2, 64, float>(smem, Wob, attT + (size_t)z * TT * CC, bo,
                            out + (size_t)z * CC * TT, 1.0f, m0, n0);
}

// ---------------------------------------------------------------------------
// Flash-style attention, 3-buffer counted-vmcnt pipeline (same scheme as the
// GEMM): stage 2 K/V-tiles ahead, per-wave PIPE_SYNC(4), no vmcnt(0) drain in
// the loop. Buffer i at kvs + i*8192: K at +0, V at +4096.
// K/V read swizzle already spans 8 column slots (lm&7) -> 2-way = free;
// left unchanged. No setprio (R2 form — best measured total).
// ---------------------------------------------------------------------------
#define ATTN_STAGE(BASE)                                \
    do {                                                \
        gld_lds16(kg, (BASE) + w * 1024);               \
        gld_lds16(kg + 512, (BASE) + w * 1024 + 512);   \
        gld_lds16(vg, (BASE) + 4096 + w * 1024);        \
        gld_lds16(vg + 8 * TT, (BASE) + 4096 + w * 1024 + 512); \
        kg += 4096;                                     \
        vg += 64;                                       \
    } while (0)

#define ATTN_STEP(BASE)                                                              \
    do {                                                                             \
        floatx4 sT[2][4];                                                            \
        _Pragma("unroll") for (int i = 0; i < 4; ++i) {                              \
            sT[0][i] = (floatx4){0.f, 0.f, 0.f, 0.f};                                \
            sT[1][i] = (floatx4){0.f, 0.f, 0.f, 0.f};                                \
        }                                                                            \
        _Pragma("unroll") for (int i = 0; i < 4; ++i) {                              \
            bf16x8 kf0 = *(bf16x8*)&(BASE)[koff + i * 1024 + cg0];                   \
            bf16x8 kf1 = *(bf16x8*)&(BASE)[koff + i * 1024 + cg1];                   \
            sT[0][i] = __builtin_amdgcn_mfma_f32_16x16x32_bf16(kf0, qf00, sT[0][i], 0, 0, 0); \
            sT[0][i] = __builtin_amdgcn_mfma_f32_16x16x32_bf16(kf1, qf01, sT[0][i], 0, 0, 0); \
            sT[1][i] = __builtin_amdgcn_mfma_f32_16x16x32_bf16(kf0, qf10, sT[1][i], 0, 0, 0); \
            sT[1][i] = __builtin_amdgcn_mfma_f32_16x16x32_bf16(kf1, qf11, sT[1][i], 0, 0, 0); \
        }                                                                            \
        float rs0 = 0.f, rs1 = 0.f;                                                  \
        _Pragma("unroll") for (int i = 0; i < 4; ++i)                                \
            _Pragma("unroll") for (int r = 0; r < 4; ++r) {                          \
                float e0 = __builtin_amdgcn_exp2f(sT[0][i][r]);                      \
                float e1 = __builtin_amdgcn_exp2f(sT[1][i][r]);                      \
                sT[0][i][r] = e0; rs0 += e0;                                         \
                sT[1][i][r] = e1; rs1 += e1;                                         \
            }                                                                        \
        rs0 += __shfl_xor(rs0, 16, 64); rs0 += __shfl_xor(rs0, 32, 64);              \
        rs1 += __shfl_xor(rs1, 16, 64); rs1 += __shfl_xor(rs1, 32, 64);              \
        l_acc0 += rs0; l_acc1 += rs1;                                                \
        _Pragma("unroll") for (int i = 0; i < 4; ++i) {                              \
            bf16x4 p0, p1;                                                           \
            _Pragma("unroll") for (int r = 0; r < 4; ++r) {                          \
                p0[r] = (__bf16)sT[0][i][r];                                         \
                p1[r] = (__bf16)sT[1][i][r];                                         \
            }                                                                        \
            *(bf16x4*)&pwl[i * 16 + lq * 4] = p0;                                    \
            *(bf16x4*)&pwl[1152 + i * 16 + lq * 4] = p1;                             \
        }                                                                            \
        asm volatile("s_waitcnt lgkmcnt(0)" ::: "memory");                           \
        __builtin_amdgcn_sched_barrier(0);                                           \
        _Pragma("unroll") for (int ss = 0; ss < 2; ++ss) {                           \
            bf16x8 ap0 = *(bf16x8*)&pwl[ss * 32 + lq * 8];                           \
            bf16x8 ap1 = *(bf16x8*)&pwl[1152 + ss * 32 + lq * 8];                    \
            const int cgv = ss ? cg1 : cg0;                                          \
            _Pragma("unroll") for (int j = 0; j < 4; ++j) {                          \
                bf16x8 vf = *(bf16x8*)&(BASE)[4096 + koff + j * 1024 + cgv];         \
                o_acc[0][j] = __builtin_amdgcn_mfma_f32_16x16x32_bf16(ap0, vf, o_acc[0][j], 0, 0, 0); \
                o_acc[1][j] = __builtin_amdgcn_mfma_f32_16x16x32_bf16(ap1, vf, o_acc[1][j], 0, 0, 0); \
            }                                                                        \
        }                                                                            \
    } while (0)

#define AITER(CUR, NXT)                                   \
    do {                                                  \
        PIPE_SYNC(4);                                     \
        ATTN_STAGE(NXT);                                  \
        ATTN_STEP(CUR);                                   \
    } while (0)

__global__ __launch_bounds__(256, 2) void attn_kernel(
    const __bf16* __restrict__ qh, const __bf16* __restrict__ kh,
    const __bf16* __restrict__ v, __bf16* __restrict__ attT) {
    const int bh = blockIdx.x, b = bh >> 4, h = bh & 15;
    const int tq0 = blockIdx.y * 128;
    const int tid = threadIdx.x, l = tid & 63, w = tid >> 6;
    const int lm = l & 15, lq = l >> 4;

    __shared__ __bf16 kvs[24576];   // 3 x (K 4096 | V 4096)
    __shared__ __bf16 p_lds[9216];  // 4 waves x [32 t][72]

    const int cg0 = (lq ^ (lm & 7)) * 8;
    const int cg1 = ((4 + lq) ^ (lm & 7)) * 8;
    const int koff = lm * 64;
    __bf16* pwl = p_lds + w * 2304 + lm * 72;

    const __bf16* qbase = qh + (size_t)bh * TT * 64 + (size_t)(tq0 + w * 32 + lm) * 64 + lq * 8;
    bf16x8 qf00 = *(const bf16x8*)(qbase);
    bf16x8 qf01 = *(const bf16x8*)(qbase + 32);
    bf16x8 qf10 = *(const bf16x8*)(qbase + 1024);
    bf16x8 qf11 = *(const bf16x8*)(qbase + 1024 + 32);

    const int srow = l >> 3, scg = l & 7;
    const int gcg = (scg ^ srow) * 8;
    const __bf16* kg = kh + (size_t)bh * TT * 64 + (size_t)(w * 16 + srow) * 64 + gcg;
    const __bf16* vg = v + (size_t)b * CC * TT + (size_t)(h * 64 + w * 16 + srow) * TT + gcg;

    floatx4 o_acc[2][4];
#pragma unroll
    for (int j = 0; j < 4; ++j) {
        o_acc[0][j] = (floatx4){0.f, 0.f, 0.f, 0.f};
        o_acc[1][j] = (floatx4){0.f, 0.f, 0.f, 0.f};
    }
    float l_acc0 = 0.f, l_acc1 = 0.f;

    __bf16* b0 = kvs;
    __bf16* b1 = kvs + 8192;
    __bf16* b2 = kvs + 16384;

    ATTN_STAGE(b0);   // tile 0
    ATTN_STAGE(b1);   // tile 1
#pragma unroll 1
    for (int st = 0; st < 12; st += 3) {
        AITER(b0, b2);    // compute st,   stage st+2
        AITER(b1, b0);    // compute st+1, stage st+3
        AITER(b2, b1);    // compute st+2, stage st+4
    }
    AITER(b0, b2);        // st=12, stage 14
    AITER(b1, b0);        // st=13, stage 15
    // st=14: only tile-15's 4 loads may remain in flight
    PIPE_SYNC(4);
    ATTN_STEP(b2);
    // st=15: drain
    PIPE_SYNC(0);
    ATTN_STEP(b0);

    float inv0[4], inv1[4];
#pragma unroll
    for (int r = 0; r < 4; ++r) {
        inv0[r] = 1.0f / __shfl(l_acc0, lq * 4 + r, 64);
        inv1[r] = 1.0f / __shfl(l_acc1, lq * 4 + r, 64);
    }
    __syncthreads();   // full drain+fence before reusing p_lds rows for output
#pragma unroll
    for (int j = 0; j < 4; ++j)
#pragma unroll
        for (int r = 0; r < 4; ++r) {
            p_lds[(w * 32 + lq * 4 + r) * 72 + j * 16 + lm] = (__bf16)(o_acc[0][j][r] * inv0[r]);
            p_lds[(w * 32 + 16 + lq * 4 + r) * 72 + j * 16 + lm] = (__bf16)(o_acc[1][j][r] * inv1[r]);
        }
    __syncthreads();
    __bf16* obase = attT + (size_t)b * TT * CC + (size_t)tq0 * CC + h * 64;
#pragma unroll
    for (int it = 0; it < 4; ++it) {
        int chunk = tid + 256 * it;
        int row = chunk >> 3, off = (chunk & 7) * 8;
        *(bf16x8*)&obase[(size_t)row * CC + off] = *(bf16x8*)&p_lds[row * 72 + off];
    }
}

// ---------------------------------------------------------------------------
extern "C" void kernel_launch(void* const* d_in, const int* in_sizes, int n_in,
                              void* d_out, int out_size, void* d_ws, size_t ws_size,
                              hipStream_t stream) {
    const float* x = (const float*)d_in[0];
    const float* c = (const float*)d_in[1];
    const float* Wq = (const float*)d_in[3];
    const float* bq = (const float*)d_in[4];
    const float* Wk = (const float*)d_in[5];
    const float* bk = (const float*)d_in[6];
    const float* Wv = (const float*)d_in[7];
    const float* bv = (const float*)d_in[8];
    const float* Wo = (const float*)d_in[9];
    const float* bo = (const float*)d_in[10];

    const size_t MB = 1024ull * 1024ull;
    char* ws = (char*)d_ws;
    __bf16* Wqb  = (__bf16*)(ws + 0 * MB);
    __bf16* Wkb  = (__bf16*)(ws + 2 * MB);
    __bf16* Wvb  = (__bf16*)(ws + 4 * MB);
    __bf16* Wob  = (__bf16*)(ws + 6 * MB);
    __bf16* xT   = (__bf16*)(ws + 8 * MB);
    __bf16* cT   = (__bf16*)(ws + 16 * MB);
    __bf16* qhb  = (__bf16*)(ws + 24 * MB);  // (b,h,t,d) roped+scaled
    __bf16* khb  = (__bf16*)(ws + 32 * MB);  // (b,h,t,d) roped
    __bf16* vbuf = (__bf16*)(ws + 40 * MB);  // (b,C,T)
    __bf16* attT = (__bf16*)(ws + 48 * MB);  // (b,t,c)

    prep_kernel<<<dim3(16, 16, 9), 256, 0, stream>>>(x, c, xT, cT, Wq, Wk, Wv, Wo,
                                                     Wqb, Wkb, Wvb, Wob);
    gemm_qkv_kernel<<<dim3(8, 8, 12), 256, 0, stream>>>(Wqb, Wkb, Wvb, xT, cT, bq, bk, bv,
                                                        qhb, khb, vbuf);
    attn_kernel<<<dim3(64, 8), 256, 0, stream>>>(qhb, khb, vbuf, attT);
    gemm_out_kernel<<<dim3(16, 8, 4), 256, 0, stream>>>(Wob, attT, bo, (float*)d_out);
}

// Round 7
// 196.968 us; speedup vs baseline: 1.0009x; 1.0009x over previous
//
#include <hip/hip_runtime.h>
#include <math.h>

#define BB 4
#define CC 1024
#define TT 1024
#define HH 16
#define HDD 64

typedef float floatx4 __attribute__((ext_vector_type(4)));
typedef __bf16 bf16x8 __attribute__((ext_vector_type(8)));
typedef __bf16 bf16x4 __attribute__((ext_vector_type(4)));
typedef unsigned uint4v __attribute__((ext_vector_type(4)));

__device__ __forceinline__ void gld_lds16(const __bf16* g, __bf16* l) {
    __builtin_amdgcn_global_load_lds(
        (__attribute__((address_space(1))) void*)(g),
        (__attribute__((address_space(3))) void*)(l), 16, 0, 0);
}

// Pack two f32 -> one u32 of 2x bf16 (lo=a, hi=b), RNE via scalar casts.
__device__ __forceinline__ unsigned pk2(float a, float b) {
    unsigned short ua = __builtin_bit_cast(unsigned short, (__bf16)a);
    unsigned short ub = __builtin_bit_cast(unsigned short, (__bf16)b);
    return (unsigned)ua | ((unsigned)ub << 16);
}

// Pipeline sync: counted vmcnt + raw barrier, sched_barrier(0)-bracketed so
// (a) prior phase's ds_reads/MFMAs cannot sink below the barrier and
// (b) next phase's ds_reads cannot hoist above it (rule #18: s_barrier is
// NOT a compiler memory fence; inline-asm waitcnt doesn't order reg-only MFMA).
#define PIPE_SYNC(VM)                                               \
    do {                                                            \
        __builtin_amdgcn_sched_barrier(0);                          \
        asm volatile("s_waitcnt vmcnt(" #VM ")" ::: "memory");      \
        __builtin_amdgcn_s_barrier();                               \
        __builtin_amdgcn_sched_barrier(0);                          \
    } while (0)

// ---------------------------------------------------------------------------
// Fused prep: z<8 -> transpose (b,C,T) f32 -> (b,T,C) bf16 for x,c;
//             z==8 -> weight f32->bf16 conversion (coalesced).
// ---------------------------------------------------------------------------
__global__ __launch_bounds__(256) void prep_kernel(
    const float* __restrict__ x, const float* __restrict__ c,
    __bf16* __restrict__ xT, __bf16* __restrict__ cT,
    const float* __restrict__ Wq, const float* __restrict__ Wk,
    const float* __restrict__ Wv, const float* __restrict__ Wo,
    __bf16* __restrict__ Wqb, __bf16* __restrict__ Wkb,
    __bf16* __restrict__ Wvb, __bf16* __restrict__ Wob) {
    __shared__ float tile[64][65];
    int tid = threadIdx.x;
    int z = blockIdx.z;
    if (z == 8) {
        const float* srcs[4] = {Wq, Wk, Wv, Wo};
        __bf16* dsts[4] = {Wqb, Wkb, Wvb, Wob};
        int bid = blockIdx.y * 16 + blockIdx.x;   // 0..255
        int mi = bid >> 6;
        const float* s = srcs[mi];
        __bf16* d = dsts[mi];
        int base = (bid & 63) * 16384;
#pragma unroll
        for (int u = 0; u < 16; ++u) {
            int idx = base + u * 1024 + tid * 4;
            float4 v4 = *(const float4*)(s + idx);
            bf16x4 o;
            o[0] = (__bf16)v4.x; o[1] = (__bf16)v4.y;
            o[2] = (__bf16)v4.z; o[3] = (__bf16)v4.w;
            *(bf16x4*)(d + idx) = o;
        }
        return;
    }
    const float* src = (z < 4) ? x : c;
    __bf16* dst = (z < 4) ? xT : cT;
    int b = z & 3;
    int t0 = blockIdx.x * 64, c0 = blockIdx.y * 64;
    int r = tid >> 2, s16 = (tid & 3) * 16;
    const float* sp = src + (size_t)b * CC * TT + (size_t)(c0 + r) * TT + t0 + s16;
    float4 a0 = *(const float4*)(sp + 0);
    float4 a1 = *(const float4*)(sp + 4);
    float4 a2 = *(const float4*)(sp + 8);
    float4 a3 = *(const float4*)(sp + 12);
    float* tr = &tile[r][s16];
    tr[0] = a0.x; tr[1] = a0.y; tr[2]  = a0.z; tr[3]  = a0.w;
    tr[4] = a1.x; tr[5] = a1.y; tr[6]  = a1.z; tr[7]  = a1.w;
    tr[8] = a2.x; tr[9] = a2.y; tr[10] = a2.z; tr[11] = a2.w;
    tr[12] = a3.x; tr[13] = a3.y; tr[14] = a3.z; tr[15] = a3.w;
    __syncthreads();
    bf16x8 p0, p1;
#pragma unroll
    for (int j = 0; j < 8; ++j) {
        p0[j] = (__bf16)tile[s16 + j][r];
        p1[j] = (__bf16)tile[s16 + 8 + j][r];
    }
    __bf16* dp = dst + (size_t)b * TT * CC + (size_t)(t0 + r) * CC + c0 + s16;
    *(bf16x8*)(dp) = p0;
    *(bf16x8*)(dp + 8) = p1;
}

// ---------------------------------------------------------------------------
// 128xBN tile (BN=128 or 64), BK=32, THREE-buffer counted-vmcnt pipeline,
// B^T input (exact R5 form — the R6 read-swizzle change re-derived to be
// conflict-equivalent at 8-lane service granularity; reverted).
// NO setprio (measured R3: m190 lockstep-GEMM regression).
// EPI 0: out bf16 (b,C,T) + bias | EPI 1: rope -> (h,t,d) | EPI 2: f32 + bias
// ---------------------------------------------------------------------------
template <int EPI, int BN, typename OutT>
__device__ __forceinline__ void gemm_bt32(
    __bf16* smem, const __bf16* __restrict__ A, const __bf16* __restrict__ Bt,
    const float* __restrict__ bias, OutT* __restrict__ out, float qs,
    int m0, int n0) {
    constexpr int BSTRIDE = 4096 + BN * 32;   // elems per pipeline buffer
    constexpr int NJ = BN / 32;               // B-fragments per wave (4 or 2)
    const int tid = threadIdx.x, l = tid & 63, w = tid >> 6;
    const int wm = (w >> 1) * 64, wn = (w & 1) * (BN / 2);
    const int lm = l & 15, lq = l >> 4;
    const int v8 = (lq ^ (lm & 3)) * 8;          // swizzled col-group (read)
    const int srow = l >> 2;                     // 0..15 staging row
    const int gcg = ((l & 3) ^ ((l >> 2) & 3)) * 8;  // global-side swizzle

    // wave w stages 32 rows of A (2 chunks) and BN/4 rows of B (2 or 1 chunk)
    const __bf16* ga = A + (size_t)(m0 + w * 32 + srow) * 1024 + gcg;
    const __bf16* gb = Bt + (size_t)(n0 + w * (BN / 4) + srow) * 1024 + gcg;
    __bf16* adst = smem + w * 1024;                 // + buffer offset
    __bf16* bdst = smem + 4096 + w * (BN / 4) * 32; // + buffer offset

#define GSTAGE(BUFOFF)                                          \
    do {                                                        \
        gld_lds16(ga, adst + (BUFOFF));                         \
        gld_lds16(ga + 16 * 1024, adst + (BUFOFF) + 512);       \
        gld_lds16(gb, bdst + (BUFOFF));                         \
        if constexpr (BN == 128)                                \
            gld_lds16(gb + 16 * 1024, bdst + (BUFOFF) + 512);   \
        ga += 32;                                               \
        gb += 32;                                               \
    } while (0)

#define GCOMP(BUFOFF)                                                          \
    do {                                                                       \
        bf16x8 af[4], bfr[NJ];                                                 \
        _Pragma("unroll") for (int i = 0; i < 4; ++i)                          \
            af[i] = *(bf16x8*)&smem[(BUFOFF) + (wm + i * 16 + lm) * 32 + v8];  \
        _Pragma("unroll") for (int j = 0; j < NJ; ++j)                         \
            bfr[j] = *(bf16x8*)&smem[(BUFOFF) + 4096 + (wn + j * 16 + lm) * 32 + v8]; \
        _Pragma("unroll") for (int i = 0; i < 4; ++i)                          \
            _Pragma("unroll") for (int j = 0; j < NJ; ++j)                     \
                acc[i][j] = __builtin_amdgcn_mfma_f32_16x16x32_bf16(af[i], bfr[j], acc[i][j], 0, 0, 0); \
    } while (0)

#define GITER(CUR, NXT)                                      \
    do {                                                     \
        if constexpr (BN == 128) PIPE_SYNC(4); else PIPE_SYNC(3); \
        GSTAGE(NXT);                                         \
        GCOMP(CUR);                                          \
    } while (0)

    floatx4 acc[4][NJ];
#pragma unroll
    for (int i = 0; i < 4; ++i)
#pragma unroll
        for (int j = 0; j < NJ; ++j) acc[i][j] = (floatx4){0.f, 0.f, 0.f, 0.f};

    GSTAGE(0);            // stage kt=0 -> buf0
    GSTAGE(BSTRIDE);      // stage kt=1 -> buf1
#pragma unroll 1
    for (int kt = 0; kt < 30; kt += 3) {
        GITER(0,           2 * BSTRIDE);  // compute kt,   stage kt+2 -> buf2
        GITER(BSTRIDE,     0);            // compute kt+1, stage kt+3 -> buf0
        GITER(2 * BSTRIDE, BSTRIDE);      // compute kt+2, stage kt+4 -> buf1
    }
    // kt=30: buf0, no further stage (only kt=31's loads may remain)
    if constexpr (BN == 128) PIPE_SYNC(4); else PIPE_SYNC(3);
    GCOMP(0);
    // kt=31: buf1, drain
    PIPE_SYNC(0);
    GCOMP(BSTRIDE);
#undef GSTAGE
#undef GCOMP
#undef GITER

    if constexpr (EPI == 1) {
        // ---- bias + RoPE in registers, write (h,t,d) via LDS bounce ----
        float b4[4][4];
#pragma unroll
        for (int i = 0; i < 4; ++i)
#pragma unroll
            for (int r = 0; r < 4; ++r) b4[i][r] = bias[m0 + wm + i * 16 + lq * 4 + r];
#pragma unroll
        for (int r = 0; r < 4; ++r) {
            // theta = 10000^(-(lq*4+r)/16)
            float theta = __expf(-0.57564627f * (float)(lq * 4 + r));
#pragma unroll
            for (int j = 0; j < 4; ++j) {
                float ang = (float)(n0 + wn + j * 16 + lm) * theta;
                float cs = __cosf(ang), sn = __sinf(ang);
                float a0 = acc[0][j][r] + b4[0][r];
                float a1 = acc[1][j][r] + b4[1][r];
                acc[0][j][r] = (a0 * cs - a1 * sn) * qs;
                acc[1][j][r] = (a1 * cs + a0 * sn) * qs;
                acc[2][j][r] = (acc[2][j][r] + b4[2][r]) * qs;
                acc[3][j][r] = (acc[3][j][r] + b4[3][r]) * qs;
            }
        }
        __syncthreads();  // full drain+fence; reuse smem as o_lds [256][72]
        const int hl = wm >> 6;
#pragma unroll
        for (int j = 0; j < 4; ++j) {
            int row = hl * 128 + wn + j * 16 + lm;
#pragma unroll
            for (int i = 0; i < 4; ++i) {
                bf16x4 pk;
#pragma unroll
                for (int r = 0; r < 4; ++r) pk[r] = (__bf16)acc[i][j][r];
                *(bf16x4*)&smem[row * 72 + i * 16 + lq * 4] = pk;
            }
        }
        __syncthreads();
        const size_t hbase = (size_t)(m0 >> 6) * (TT * 64);
#pragma unroll
        for (int it = 0; it < 8; ++it) {
            int chunk = tid + 256 * it;
            int row = chunk >> 3, off = (chunk & 7) * 8;  // row 0..255
            int hh = row >> 7, t = n0 + (row & 127);
            *(bf16x8*)&out[hbase + (size_t)hh * (TT * 64) + (size_t)t * 64 + off] =
                *(bf16x8*)&smem[row * 72 + off];
        }
    } else {
#pragma unroll
        for (int i = 0; i < 4; ++i) {
            int mbase = m0 + wm + i * 16 + lq * 4;
#pragma unroll
            for (int r = 0; r < 4; ++r) {
                float bv = bias[mbase + r];
                size_t rowoff = (size_t)(mbase + r) * 1024 + n0 + wn + lm;
#pragma unroll
                for (int j = 0; j < NJ; ++j)
                    out[rowoff + j * 16] = (OutT)(acc[i][j][r] + bv);
            }
        }
    }
}

// T1: XCD-aware chunked swizzle. nwg is a multiple of 8 (768 / 512) ->
// bijective. XCD k gets a contiguous chunk of nwg/8 tiles, so shared A/B
// panels stay in one XCD's L2 (measured R3/R4: FETCH 37.0 -> 32.0 MB).
__global__ __launch_bounds__(256) void gemm_qkv_kernel(
    const __bf16* __restrict__ Wqb, const __bf16* __restrict__ Wkb, const __bf16* __restrict__ Wvb,
    const __bf16* __restrict__ xT, const __bf16* __restrict__ cT,
    const float* __restrict__ bq, const float* __restrict__ bk, const float* __restrict__ bv,
    __bf16* __restrict__ qhb, __bf16* __restrict__ khb, __bf16* __restrict__ vb) {
    __shared__ __bf16 smem[24576];  // 48 KB: 3 pipeline buffers; epilogue reuse
    int lin = blockIdx.x + 8 * blockIdx.y + 64 * blockIdx.z;   // 0..767
    int swz = (lin & 7) * 96 + (lin >> 3);                     // XCD-chunked
    int z = swz >> 6, rem = swz & 63;
    int m0 = (rem >> 3) * 128, n0 = (rem & 7) * 128;
    int which = z >> 2, b = z & 3;
    if (which == 0) {
        gemm_bt32<1, 128, __bf16>(smem, Wqb, xT + (size_t)b * TT * CC, bq,
                                  qhb + (size_t)b * HH * TT * 64, 0.18033688f, m0, n0);
    } else if (which == 1) {
        gemm_bt32<1, 128, __bf16>(smem, Wkb, cT + (size_t)b * TT * CC, bk,
                                  khb + (size_t)b * HH * TT * 64, 1.0f, m0, n0);
    } else {
        gemm_bt32<0, 128, __bf16>(smem, Wvb, cT + (size_t)b * TT * CC, bv,
                                  vb + (size_t)b * CC * TT, 1.0f, m0, n0);
    }
}

// 128x64 tiles: grid 512 = 2 blocks/CU. LDS 36 KB.
__global__ __launch_bounds__(256) void gemm_out_kernel(
    const __bf16* __restrict__ Wob, const __bf16* __restrict__ attT,
    const float* __restrict__ bo, float* __restrict__ out) {
    __shared__ __bf16 smem[18432];  // 3 x 6144-elem buffers
    int lin = blockIdx.x + 16 * blockIdx.y + 128 * blockIdx.z;  // 0..511
    int swz = (lin & 7) * 64 + (lin >> 3);                      // XCD-chunked
    int z = swz >> 7, rem = swz & 127;
    int m0 = (rem >> 4) * 128, n0 = (rem & 15) * 64;
    gemm_bt32<2, 64, float>(smem, Wob, attT + (size_t)z * TT * CC, bo,
                            out + (size_t)z * CC * TT, 1.0f, m0, n0);
}

// ---------------------------------------------------------------------------
// Flash-style attention v2: 8 waves x 16 q-rows, 3-buffer counted-vmcnt K/V
// pipeline (PIPE_SYNC(2): 2 loads/wave/stage), and IN-REGISTER P
// redistribution (no P LDS round-trip, p_lds deleted -> LDS 48 KB).
//
// After QK^T (A=K, B=Q), lane (lm,lq) holds P[q=lm][k=i*16+lq*4+r].
// PV needs A-fragment P[q=lm][k=lq*8..lq*8+7] per 32-k half ss.
// Routing (within lq-groups, lanes +-16/32/48), derived & spot-verified:
//   dest lq0: w0,w1 = own pkE     ; w2,w3 = xor16 (lq1's pkE)
//   dest lq1: w0,w1 = xor48 (lq2's pkE) ; w2,w3 = xor32 (lq3's pkE)
//   dest lq2: w0,w1 = xor32 (lq0's pkO) ; w2,w3 = xor48 (lq1's pkO)
//   dest lq3: w0,w1 = xor16 (lq2's pkO) ; w2,w3 = own pkO
// where pkE = pack(sT[ss*2]), pkO = pack(sT[ss*2+1]), words = k pairs.
// Epilogue output bounce reuses kvs (dead after the loop).
// ---------------------------------------------------------------------------
#define ATTN_STAGE(BASE)                          \
    do {                                          \
        gld_lds16(sg, (BASE) + sdoff);            \
        gld_lds16(sg + soff2, (BASE) + sdoff + 512); \
        sg += sstep;                              \
    } while (0)

#define ATTN_STEP(BASE)                                                              \
    do {                                                                             \
        floatx4 sT[4];                                                               \
        _Pragma("unroll") for (int i = 0; i < 4; ++i)                                \
            sT[i] = (floatx4){0.f, 0.f, 0.f, 0.f};                                   \
        _Pragma("unroll") for (int i = 0; i < 4; ++i) {                              \
            bf16x8 kf0 = *(bf16x8*)&(BASE)[koff + i * 1024 + cg0];                   \
            bf16x8 kf1 = *(bf16x8*)&(BASE)[koff + i * 1024 + cg1];                   \
            sT[i] = __builtin_amdgcn_mfma_f32_16x16x32_bf16(kf0, qf0, sT[i], 0, 0, 0); \
            sT[i] = __builtin_amdgcn_mfma_f32_16x16x32_bf16(kf1, qf1, sT[i], 0, 0, 0); \
        }                                                                            \
        float rs = 0.f;                                                              \
        _Pragma("unroll") for (int i = 0; i < 4; ++i)                                \
            _Pragma("unroll") for (int r = 0; r < 4; ++r) {                          \
                float e = __builtin_amdgcn_exp2f(sT[i][r]);                          \
                sT[i][r] = e; rs += e;                                               \
            }                                                                        \
        rs += __shfl_xor(rs, 16, 64); rs += __shfl_xor(rs, 32, 64);                  \
        l_acc += rs;                                                                 \
        unsigned pk0a = pk2(sT[0][0], sT[0][1]), pk0b = pk2(sT[0][2], sT[0][3]);     \
        unsigned pk1a = pk2(sT[1][0], sT[1][1]), pk1b = pk2(sT[1][2], sT[1][3]);     \
        unsigned pk2a = pk2(sT[2][0], sT[2][1]), pk2b = pk2(sT[2][2], sT[2][3]);     \
        unsigned pk3a = pk2(sT[3][0], sT[3][1]), pk3b = pk2(sT[3][2], sT[3][3]);     \
        _Pragma("unroll") for (int ss = 0; ss < 2; ++ss) {                           \
            unsigned pE0 = ss ? pk2a : pk0a, pE1 = ss ? pk2b : pk0b;                 \
            unsigned pO0 = ss ? pk3a : pk1a, pO1 = ss ? pk3b : pk1b;                 \
            unsigned r16_0 = __shfl_xor((lq == 1) ? pE0 : pO0, 16, 64);              \
            unsigned r16_1 = __shfl_xor((lq == 1) ? pE1 : pO1, 16, 64);              \
            unsigned r32_0 = __shfl_xor((lq == 3) ? pE0 : pO0, 32, 64);              \
            unsigned r32_1 = __shfl_xor((lq == 3) ? pE1 : pO1, 32, 64);              \
            unsigned r48_0 = __shfl_xor((lq == 2) ? pE0 : pO0, 48, 64);              \
            unsigned r48_1 = __shfl_xor((lq == 2) ? pE1 : pO1, 48, 64);              \
            uint4v wv;                                                               \
            wv[0] = (lq == 0) ? pE0 : (lq == 1) ? r48_0 : (lq == 2) ? r32_0 : r16_0; \
            wv[1] = (lq == 0) ? pE1 : (lq == 1) ? r48_1 : (lq == 2) ? r32_1 : r16_1; \
            wv[2] = (lq == 0) ? r16_0 : (lq == 1) ? r32_0 : (lq == 2) ? r48_0 : pO0; \
            wv[3] = (lq == 0) ? r16_1 : (lq == 1) ? r32_1 : (lq == 2) ? r48_1 : pO1; \
            bf16x8 ap = __builtin_bit_cast(bf16x8, wv);                              \
            const int cgv = ss ? cg1 : cg0;                                          \
            _Pragma("unroll") for (int j = 0; j < 4; ++j) {                          \
                bf16x8 vf = *(bf16x8*)&(BASE)[4096 + koff + j * 1024 + cgv];         \
                o_acc[j] = __builtin_amdgcn_mfma_f32_16x16x32_bf16(ap, vf, o_acc[j], 0, 0, 0); \
            }                                                                        \
        }                                                                            \
    } while (0)

#define AITER(CUR, NXT)                                   \
    do {                                                  \
        PIPE_SYNC(2);                                     \
        ATTN_STAGE(NXT);                                  \
        ATTN_STEP(CUR);                                   \
    } while (0)

__global__ __launch_bounds__(512, 4) void attn_kernel(
    const __bf16* __restrict__ qh, const __bf16* __restrict__ kh,
    const __bf16* __restrict__ v, __bf16* __restrict__ attT) {
    const int bh = blockIdx.x, b = bh >> 4, h = bh & 15;
    const int tq0 = blockIdx.y * 128;
    const int tid = threadIdx.x, l = tid & 63, w = tid >> 6;  // w 0..7
    const int lm = l & 15, lq = l >> 4;

    __shared__ __bf16 kvs[24576];   // 3 x (K 4096 | V 4096); epilogue reuse

    const int cg0 = (lq ^ (lm & 7)) * 8;
    const int cg1 = ((4 + lq) ^ (lm & 7)) * 8;
    const int koff = lm * 64;

    // Q fragments: this wave's 16 q-rows = tq0 + w*16 + lm
    const __bf16* qbase = qh + (size_t)bh * TT * 64 + (size_t)(tq0 + w * 16 + lm) * 64 + lq * 8;
    bf16x8 qf0 = *(const bf16x8*)(qbase);
    bf16x8 qf1 = *(const bf16x8*)(qbase + 32);

    // Staging: waves 0-3 -> K rows w*16..+15; waves 4-7 -> V d-rows (w-4)*16..
    const int srow = l >> 3, scg = l & 7;
    const int gcg = (scg ^ srow) * 8;
    const __bf16* sg;
    int sstep, soff2, sdoff;
    if (w < 4) {
        sg = kh + (size_t)bh * TT * 64 + (size_t)(w * 16 + srow) * 64 + gcg;
        sstep = 4096; soff2 = 512; sdoff = w * 1024;
    } else {
        sg = v + (size_t)b * CC * TT + (size_t)(h * 64 + (w - 4) * 16 + srow) * TT + gcg;
        sstep = 64; soff2 = 8 * TT; sdoff = 4096 + (w - 4) * 1024;
    }

    floatx4 o_acc[4];
#pragma unroll
    for (int j = 0; j < 4; ++j) o_acc[j] = (floatx4){0.f, 0.f, 0.f, 0.f};
    float l_acc = 0.f;

    __bf16* b0 = kvs;
    __bf16* b1 = kvs + 8192;
    __bf16* b2 = kvs + 16384;

    ATTN_STAGE(b0);   // tile 0
    ATTN_STAGE(b1);   // tile 1
#pragma unroll 1
    for (int st = 0; st < 12; st += 3) {
        AITER(b0, b2);    // compute st,   stage st+2
        AITER(b1, b0);    // compute st+1, stage st+3
        AITER(b2, b1);    // compute st+2, stage st+4
    }
    AITER(b0, b2);        // st=12, stage 14
    AITER(b1, b0);        // st=13, stage 15
    // st=14: only tile-15's 2 own loads may remain in flight
    PIPE_SYNC(2);
    ATTN_STEP(b2);
    // st=15: drain
    PIPE_SYNC(0);
    ATTN_STEP(b0);

    float inv[4];
#pragma unroll
    for (int r = 0; r < 4; ++r)
        inv[r] = 1.0f / __shfl(l_acc, lq * 4 + r, 64);

    __syncthreads();   // loop reads done in all waves; kvs now reusable
#pragma unroll
    for (int j = 0; j < 4; ++j)
#pragma unroll
        for (int r = 0; r < 4; ++r)
            kvs[(w * 16 + lq * 4 + r) * 72 + j * 16 + lm] = (__bf16)(o_acc[j][r] * inv[r]);
    __syncthreads();
    __bf16* obase = attT + (size_t)b * TT * CC + (size_t)tq0 * CC + h * 64;
#pragma unroll
    for (int it = 0; it < 2; ++it) {
        int chunk = tid + 512 * it;             // 0..1023
        int row = chunk >> 3, off = (chunk & 7) * 8;  // row 0..127
        *(bf16x8*)&obase[(size_t)row * CC + off] = *(bf16x8*)&kvs[row * 72 + off];
    }
}

// ---------------------------------------------------------------------------
extern "C" void kernel_launch(void* const* d_in, const int* in_sizes, int n_in,
                              void* d_out, int out_size, void* d_ws, size_t ws_size,
                              hipStream_t stream) {
    const float* x = (const float*)d_in[0];
    const float* c = (const float*)d_in[1];
    const float* Wq = (const float*)d_in[3];
    const float* bq = (const float*)d_in[4];
    const float* Wk = (const float*)d_in[5];
    const float* bk = (const float*)d_in[6];
    const float* Wv = (const float*)d_in[7];
    const float* bv = (const float*)d_in[8];
    const float* Wo = (const float*)d_in[9];
    const float* bo = (const float*)d_in[10];

    const size_t MB = 1024ull * 1024ull;
    char* ws = (char*)d_ws;
    __bf16* Wqb  = (__bf16*)(ws + 0 * MB);
    __bf16* Wkb  = (__bf16*)(ws + 2 * MB);
    __bf16* Wvb  = (__bf16*)(ws + 4 * MB);
    __bf16* Wob  = (__bf16*)(ws + 6 * MB);
    __bf16* xT   = (__bf16*)(ws + 8 * MB);
    __bf16* cT   = (__bf16*)(ws + 16 * MB);
    __bf16* qhb  = (__bf16*)(ws + 24 * MB);  // (b,h,t,d) roped+scaled
    __bf16* khb  = (__bf16*)(ws + 32 * MB);  // (b,h,t,d) roped
    __bf16* vbuf = (__bf16*)(ws + 40 * MB);  // (b,C,T)
    __bf16* attT = (__bf16*)(ws + 48 * MB);  // (b,t,c)

    prep_kernel<<<dim3(16, 16, 9), 256, 0, stream>>>(x, c, xT, cT, Wq, Wk, Wv, Wo,
                                                     Wqb, Wkb, Wvb, Wob);
    gemm_qkv_kernel<<<dim3(8, 8, 12), 256, 0, stream>>>(Wqb, Wkb, Wvb, xT, cT, bq, bk, bv,
                                                        qhb, khb, vbuf);
    attn_kernel<<<dim3(64, 8), 512, 0, stream>>>(qhb, khb, vbuf, attT);
    gemm_out_kernel<<<dim3(16, 8, 4), 256, 0, stream>>>(Wob, attT, bo, (float*)d_out);
}

// Round 8
// 188.941 us; speedup vs baseline: 1.0434x; 1.0425x over previous
//
#include <hip/hip_runtime.h>
#include <math.h>

#define BB 4
#define CC 1024
#define TT 1024
#define HH 16
#define HDD 64

typedef float floatx4 __attribute__((ext_vector_type(4)));
typedef __bf16 bf16x8 __attribute__((ext_vector_type(8)));
typedef __bf16 bf16x4 __attribute__((ext_vector_type(4)));

__device__ __forceinline__ void gld_lds16(const __bf16* g, __bf16* l) {
    __builtin_amdgcn_global_load_lds(
        (__attribute__((address_space(1))) void*)(g),
        (__attribute__((address_space(3))) void*)(l), 16, 0, 0);
}

// Pipeline sync: counted vmcnt + raw barrier, sched_barrier(0)-bracketed so
// (a) prior phase's ds_reads/MFMAs cannot sink below the barrier and
// (b) next phase's ds_reads cannot hoist above it (rule #18: s_barrier is
// NOT a compiler memory fence; inline-asm waitcnt doesn't order reg-only MFMA).
#define PIPE_SYNC(VM)                                               \
    do {                                                            \
        __builtin_amdgcn_sched_barrier(0);                          \
        asm volatile("s_waitcnt vmcnt(" #VM ")" ::: "memory");      \
        __builtin_amdgcn_s_barrier();                               \
        __builtin_amdgcn_sched_barrier(0);                          \
    } while (0)

// ---------------------------------------------------------------------------
// Fused prep: z<8 -> transpose (b,C,T) f32 -> (b,T,C) bf16 for x,c;
//             z==8 -> weight f32->bf16 conversion (coalesced).
// ---------------------------------------------------------------------------
__global__ __launch_bounds__(256) void prep_kernel(
    const float* __restrict__ x, const float* __restrict__ c,
    __bf16* __restrict__ xT, __bf16* __restrict__ cT,
    const float* __restrict__ Wq, const float* __restrict__ Wk,
    const float* __restrict__ Wv, const float* __restrict__ Wo,
    __bf16* __restrict__ Wqb, __bf16* __restrict__ Wkb,
    __bf16* __restrict__ Wvb, __bf16* __restrict__ Wob) {
    __shared__ float tile[64][65];
    int tid = threadIdx.x;
    int z = blockIdx.z;
    if (z == 8) {
        const float* srcs[4] = {Wq, Wk, Wv, Wo};
        __bf16* dsts[4] = {Wqb, Wkb, Wvb, Wob};
        int bid = blockIdx.y * 16 + blockIdx.x;   // 0..255
        int mi = bid >> 6;
        const float* s = srcs[mi];
        __bf16* d = dsts[mi];
        int base = (bid & 63) * 16384;
#pragma unroll
        for (int u = 0; u < 16; ++u) {
            int idx = base + u * 1024 + tid * 4;
            float4 v4 = *(const float4*)(s + idx);
            bf16x4 o;
            o[0] = (__bf16)v4.x; o[1] = (__bf16)v4.y;
            o[2] = (__bf16)v4.z; o[3] = (__bf16)v4.w;
            *(bf16x4*)(d + idx) = o;
        }
        return;
    }
    const float* src = (z < 4) ? x : c;
    __bf16* dst = (z < 4) ? xT : cT;
    int b = z & 3;
    int t0 = blockIdx.x * 64, c0 = blockIdx.y * 64;
    int r = tid >> 2, s16 = (tid & 3) * 16;
    const float* sp = src + (size_t)b * CC * TT + (size_t)(c0 + r) * TT + t0 + s16;
    float4 a0 = *(const float4*)(sp + 0);
    float4 a1 = *(const float4*)(sp + 4);
    float4 a2 = *(const float4*)(sp + 8);
    float4 a3 = *(const float4*)(sp + 12);
    float* tr = &tile[r][s16];
    tr[0] = a0.x; tr[1] = a0.y; tr[2]  = a0.z; tr[3]  = a0.w;
    tr[4] = a1.x; tr[5] = a1.y; tr[6]  = a1.z; tr[7]  = a1.w;
    tr[8] = a2.x; tr[9] = a2.y; tr[10] = a2.z; tr[11] = a2.w;
    tr[12] = a3.x; tr[13] = a3.y; tr[14] = a3.z; tr[15] = a3.w;
    __syncthreads();
    bf16x8 p0, p1;
#pragma unroll
    for (int j = 0; j < 8; ++j) {
        p0[j] = (__bf16)tile[s16 + j][r];
        p1[j] = (__bf16)tile[s16 + 8 + j][r];
    }
    __bf16* dp = dst + (size_t)b * TT * CC + (size_t)(t0 + r) * CC + c0 + s16;
    *(bf16x8*)(dp) = p0;
    *(bf16x8*)(dp + 8) = p1;
}

// ---------------------------------------------------------------------------
// 128x128 tile, BK=32, THREE-buffer counted-vmcnt pipeline, B^T input.
// Stage is issued 2 K-tiles ahead; each wave waits only its OWN stage-k loads
// (s_waitcnt vmcnt(4): newest stage stays in flight) then raw s_barrier.
// No vmcnt(0) drain in the main loop (T4). Buffer i at elem offset i*8192:
// A [128][32] at +0, B [128][32] at +4096 (16 KB/buffer, 48 KB total).
// Epilogue reuses smem as [256][72] (18432 elems <= 24576).
// Cross-wave safety (with PIPE_SYNC fences): wave reaches barrier k only
// after its GCOMP(k-1) ds_reads completed (pinned above the barrier), so
// staging buf (k+2)%3 after barrier k cannot race readers of buf (k-1)%3.
// EPI 0: out bf16 (b,C,T) + bias | EPI 1: rope -> (h,t,d) | EPI 2: f32 + bias
// ---------------------------------------------------------------------------
template <int EPI, typename OutT>
__device__ __forceinline__ void gemm_bt32(
    __bf16* smem, const __bf16* __restrict__ A, const __bf16* __restrict__ Bt,
    const float* __restrict__ bias, OutT* __restrict__ out, float qs) {
    const int tid = threadIdx.x, l = tid & 63, w = tid >> 6;
    const int m0 = blockIdx.y * 128, n0 = blockIdx.x * 128;
    const int wm = (w >> 1) * 64, wn = (w & 1) * 64;
    const int lm = l & 15, lq = l >> 4;
    const int v8 = (lq ^ (lm & 3)) * 8;          // swizzled col-group (read)
    const int srow = l >> 2;                     // 0..15 staging row
    const int gcg = ((l & 3) ^ ((l >> 2) & 3)) * 8;  // global-side swizzle

    // wave w stages rows w*32..w*32+31 of A and B (2 chunks of 16 rows each)
    const __bf16* ga = A + (size_t)(m0 + w * 32 + srow) * 1024 + gcg;
    const __bf16* gb = Bt + (size_t)(n0 + w * 32 + srow) * 1024 + gcg;
    __bf16* adst = smem + w * 1024;          // + buffer offset
    __bf16* bdst = smem + 4096 + w * 1024;

#define GSTAGE(BUFOFF)                                       \
    do {                                                     \
        gld_lds16(ga, adst + (BUFOFF));                      \
        gld_lds16(ga + 16 * 1024, adst + (BUFOFF) + 512);    \
        gld_lds16(gb, bdst + (BUFOFF));                      \
        gld_lds16(gb + 16 * 1024, bdst + (BUFOFF) + 512);    \
        ga += 32;                                            \
        gb += 32;                                            \
    } while (0)

#define GCOMP(BUFOFF)                                                          \
    do {                                                                       \
        bf16x8 af[4], bfr[4];                                                  \
        _Pragma("unroll") for (int i = 0; i < 4; ++i)                          \
            af[i] = *(bf16x8*)&smem[(BUFOFF) + (wm + i * 16 + lm) * 32 + v8];  \
        _Pragma("unroll") for (int j = 0; j < 4; ++j)                          \
            bfr[j] = *(bf16x8*)&smem[(BUFOFF) + 4096 + (wn + j * 16 + lm) * 32 + v8]; \
        _Pragma("unroll") for (int i = 0; i < 4; ++i)                          \
            _Pragma("unroll") for (int j = 0; j < 4; ++j)                      \
                acc[i][j] = __builtin_amdgcn_mfma_f32_16x16x32_bf16(af[i], bfr[j], acc[i][j], 0, 0, 0); \
    } while (0)

#define GITER(CUR, NXT, VM)                                  \
    do {                                                     \
        PIPE_SYNC(VM);                                       \
        GSTAGE(NXT);                                         \
        GCOMP(CUR);                                          \
    } while (0)

    floatx4 acc[4][4];
#pragma unroll
    for (int i = 0; i < 4; ++i)
#pragma unroll
        for (int j = 0; j < 4; ++j) acc[i][j] = (floatx4){0.f, 0.f, 0.f, 0.f};

    GSTAGE(0);      // stage kt=0 -> buf0
    GSTAGE(8192);   // stage kt=1 -> buf1
#pragma unroll 1
    for (int kt = 0; kt < 30; kt += 3) {
        GITER(0,     16384, 4);   // compute kt,   stage kt+2 -> buf2
        GITER(8192,  0,     4);   // compute kt+1, stage kt+3 -> buf0
        GITER(16384, 8192,  4);   // compute kt+2, stage kt+4 -> buf1
    }
    // kt=30: buf0, no further stage (only kt=31's 4 loads may remain)
    PIPE_SYNC(4);
    GCOMP(0);
    // kt=31: buf1, drain
    PIPE_SYNC(0);
    GCOMP(8192);
#undef GSTAGE
#undef GCOMP
#undef GITER

    if (EPI == 1) {
        // ---- bias + RoPE in registers, write (h,t,d) via LDS bounce ----
        float b4[4][4];
#pragma unroll
        for (int i = 0; i < 4; ++i)
#pragma unroll
            for (int r = 0; r < 4; ++r) b4[i][r] = bias[m0 + wm + i * 16 + lq * 4 + r];
#pragma unroll
        for (int r = 0; r < 4; ++r) {
            // theta = 10000^(-(lq*4+r)/16)
            float theta = __expf(-0.57564627f * (float)(lq * 4 + r));
#pragma unroll
            for (int j = 0; j < 4; ++j) {
                float ang = (float)(n0 + wn + j * 16 + lm) * theta;
                float cs = __cosf(ang), sn = __sinf(ang);
                float a0 = acc[0][j][r] + b4[0][r];
                float a1 = acc[1][j][r] + b4[1][r];
                acc[0][j][r] = (a0 * cs - a1 * sn) * qs;
                acc[1][j][r] = (a1 * cs + a0 * sn) * qs;
                acc[2][j][r] = (acc[2][j][r] + b4[2][r]) * qs;
                acc[3][j][r] = (acc[3][j][r] + b4[3][r]) * qs;
            }
        }
        __syncthreads();  // full drain+fence; reuse smem as o_lds [256][72]
        const int hl = wm >> 6;
#pragma unroll
        for (int j = 0; j < 4; ++j) {
            int row = hl * 128 + wn + j * 16 + lm;
#pragma unroll
            for (int i = 0; i < 4; ++i) {
                bf16x4 pk;
#pragma unroll
                for (int r = 0; r < 4; ++r) pk[r] = (__bf16)acc[i][j][r];
                *(bf16x4*)&smem[row * 72 + i * 16 + lq * 4] = pk;
            }
        }
        __syncthreads();
        const size_t hbase = (size_t)(m0 >> 6) * (TT * 64);
#pragma unroll
        for (int it = 0; it < 8; ++it) {
            int chunk = tid + 256 * it;
            int row = chunk >> 3, off = (chunk & 7) * 8;  // row 0..255
            int hh = row >> 7, t = n0 + (row & 127);
            *(bf16x8*)&out[hbase + (size_t)hh * (TT * 64) + (size_t)t * 64 + off] =
                *(bf16x8*)&smem[row * 72 + off];
        }
    } else {
#pragma unroll
        for (int i = 0; i < 4; ++i) {
            int mbase = m0 + wm + i * 16 + lq * 4;
#pragma unroll
            for (int r = 0; r < 4; ++r) {
                float bv = bias[mbase + r];
                size_t rowoff = (size_t)(mbase + r) * 1024 + n0 + wn + lm;
#pragma unroll
                for (int j = 0; j < 4; ++j)
                    out[rowoff + j * 16] = (OutT)(acc[i][j][r] + bv);
            }
        }
    }
}

__global__ __launch_bounds__(256) void gemm_qkv_kernel(
    const __bf16* __restrict__ Wqb, const __bf16* __restrict__ Wkb, const __bf16* __restrict__ Wvb,
    const __bf16* __restrict__ xT, const __bf16* __restrict__ cT,
    const float* __restrict__ bq, const float* __restrict__ bk, const float* __restrict__ bv,
    __bf16* __restrict__ qhb, __bf16* __restrict__ khb, __bf16* __restrict__ vb) {
    __shared__ __bf16 smem[24576];  // 48 KB: 3 pipeline buffers; epilogue reuse
    int z = blockIdx.z, which = z >> 2, b = z & 3;
    if (which == 0) {
        gemm_bt32<1, __bf16>(smem, Wqb, xT + (size_t)b * TT * CC, bq,
                             qhb + (size_t)b * HH * TT * 64, 0.18033688f);
    } else if (which == 1) {
        gemm_bt32<1, __bf16>(smem, Wkb, cT + (size_t)b * TT * CC, bk,
                             khb + (size_t)b * HH * TT * 64, 1.0f);
    } else {
        gemm_bt32<0, __bf16>(smem, Wvb, cT + (size_t)b * TT * CC, bv,
                             vb + (size_t)b * CC * TT, 1.0f);
    }
}

__global__ __launch_bounds__(256) void gemm_out_kernel(
    const __bf16* __restrict__ Wob, const __bf16* __restrict__ attT,
    const float* __restrict__ bo, float* __restrict__ out) {
    __shared__ __bf16 smem[24576];
    int b = blockIdx.z;
    gemm_bt32<2, float>(smem, Wob, attT + (size_t)b * TT * CC, bo,
                        out + (size_t)b * CC * TT, 1.0f);
}

// ---------------------------------------------------------------------------
// Flash-style attention, 3-buffer counted-vmcnt pipeline (same scheme as the
// GEMM): stage 2 K/V-tiles ahead, per-wave PIPE_SYNC(4), no vmcnt(0) drain in
// the loop. Buffer i at kvs + i*8192: K at +0, V at +4096.
// ---------------------------------------------------------------------------
#define ATTN_STAGE(BASE)                                \
    do {                                                \
        gld_lds16(kg, (BASE) + w * 1024);               \
        gld_lds16(kg + 512, (BASE) + w * 1024 + 512);   \
        gld_lds16(vg, (BASE) + 4096 + w * 1024);        \
        gld_lds16(vg + 8 * TT, (BASE) + 4096 + w * 1024 + 512); \
        kg += 4096;                                     \
        vg += 64;                                       \
    } while (0)

#define ATTN_STEP(BASE)                                                              \
    do {                                                                             \
        floatx4 sT[2][4];                                                            \
        _Pragma("unroll") for (int i = 0; i < 4; ++i) {                              \
            sT[0][i] = (floatx4){0.f, 0.f, 0.f, 0.f};                                \
            sT[1][i] = (floatx4){0.f, 0.f, 0.f, 0.f};                                \
        }                                                                            \
        _Pragma("unroll") for (int i = 0; i < 4; ++i) {                              \
            bf16x8 kf0 = *(bf16x8*)&(BASE)[koff + i * 1024 + cg0];                   \
            bf16x8 kf1 = *(bf16x8*)&(BASE)[koff + i * 1024 + cg1];                   \
            sT[0][i] = __builtin_amdgcn_mfma_f32_16x16x32_bf16(kf0, qf00, sT[0][i], 0, 0, 0); \
            sT[0][i] = __builtin_amdgcn_mfma_f32_16x16x32_bf16(kf1, qf01, sT[0][i], 0, 0, 0); \
            sT[1][i] = __builtin_amdgcn_mfma_f32_16x16x32_bf16(kf0, qf10, sT[1][i], 0, 0, 0); \
            sT[1][i] = __builtin_amdgcn_mfma_f32_16x16x32_bf16(kf1, qf11, sT[1][i], 0, 0, 0); \
        }                                                                            \
        float rs0 = 0.f, rs1 = 0.f;                                                  \
        _Pragma("unroll") for (int i = 0; i < 4; ++i)                                \
            _Pragma("unroll") for (int r = 0; r < 4; ++r) {                          \
                float e0 = __builtin_amdgcn_exp2f(sT[0][i][r]);                      \
                float e1 = __builtin_amdgcn_exp2f(sT[1][i][r]);                      \
                sT[0][i][r] = e0; rs0 += e0;                                         \
                sT[1][i][r] = e1; rs1 += e1;                                         \
            }                                                                        \
        rs0 += __shfl_xor(rs0, 16, 64); rs0 += __shfl_xor(rs0, 32, 64);              \
        rs1 += __shfl_xor(rs1, 16, 64); rs1 += __shfl_xor(rs1, 32, 64);              \
        l_acc0 += rs0; l_acc1 += rs1;                                                \
        _Pragma("unroll") for (int i = 0; i < 4; ++i) {                              \
            bf16x4 p0, p1;                                                           \
            _Pragma("unroll") for (int r = 0; r < 4; ++r) {                          \
                p0[r] = (__bf16)sT[0][i][r];                                         \
                p1[r] = (__bf16)sT[1][i][r];                                         \
            }                                                                        \
            *(bf16x4*)&pwl[i * 16 + lq * 4] = p0;                                    \
            *(bf16x4*)&pwl[1152 + i * 16 + lq * 4] = p1;                             \
        }                                                                            \
        asm volatile("s_waitcnt lgkmcnt(0)" ::: "memory");                           \
        __builtin_amdgcn_sched_barrier(0);                                           \
        _Pragma("unroll") for (int ss = 0; ss < 2; ++ss) {                           \
            bf16x8 ap0 = *(bf16x8*)&pwl[ss * 32 + lq * 8];                           \
            bf16x8 ap1 = *(bf16x8*)&pwl[1152 + ss * 32 + lq * 8];                    \
            const int cgv = ss ? cg1 : cg0;                                          \
            _Pragma("unroll") for (int j = 0; j < 4; ++j) {                          \
                bf16x8 vf = *(bf16x8*)&(BASE)[4096 + koff + j * 1024 + cgv];         \
                o_acc[0][j] = __builtin_amdgcn_mfma_f32_16x16x32_bf16(ap0, vf, o_acc[0][j], 0, 0, 0); \
                o_acc[1][j] = __builtin_amdgcn_mfma_f32_16x16x32_bf16(ap1, vf, o_acc[1][j], 0, 0, 0); \
            }                                                                        \
        }                                                                            \
    } while (0)

#define AITER(CUR, NXT)                                   \
    do {                                                  \
        PIPE_SYNC(4);                                     \
        ATTN_STAGE(NXT);                                  \
        ATTN_STEP(CUR);                                   \
    } while (0)

__global__ __launch_bounds__(256, 2) void attn_kernel(
    const __bf16* __restrict__ qh, const __bf16* __restrict__ kh,
    const __bf16* __restrict__ v, __bf16* __restrict__ attT) {
    const int bh = blockIdx.x, b = bh >> 4, h = bh & 15;
    const int tq0 = blockIdx.y * 128;
    const int tid = threadIdx.x, l = tid & 63, w = tid >> 6;
    const int lm = l & 15, lq = l >> 4;

    __shared__ __bf16 kvs[24576];   // 3 x (K 4096 | V 4096)
    __shared__ __bf16 p_lds[9216];  // 4 waves x [32 t][72]

    const int cg0 = (lq ^ (lm & 7)) * 8;
    const int cg1 = ((4 + lq) ^ (lm & 7)) * 8;
    const int koff = lm * 64;
    __bf16* pwl = p_lds + w * 2304 + lm * 72;

    const __bf16* qbase = qh + (size_t)bh * TT * 64 + (size_t)(tq0 + w * 32 + lm) * 64 + lq * 8;
    bf16x8 qf00 = *(const bf16x8*)(qbase);
    bf16x8 qf01 = *(const bf16x8*)(qbase + 32);
    bf16x8 qf10 = *(const bf16x8*)(qbase + 1024);
    bf16x8 qf11 = *(const bf16x8*)(qbase + 1024 + 32);

    const int srow = l >> 3, scg = l & 7;
    const int gcg = (scg ^ srow) * 8;
    const __bf16* kg = kh + (size_t)bh * TT * 64 + (size_t)(w * 16 + srow) * 64 + gcg;
    const __bf16* vg = v + (size_t)b * CC * TT + (size_t)(h * 64 + w * 16 + srow) * TT + gcg;

    floatx4 o_acc[2][4];
#pragma unroll
    for (int j = 0; j < 4; ++j) {
        o_acc[0][j] = (floatx4){0.f, 0.f, 0.f, 0.f};
        o_acc[1][j] = (floatx4){0.f, 0.f, 0.f, 0.f};
    }
    float l_acc0 = 0.f, l_acc1 = 0.f;

    __bf16* b0 = kvs;
    __bf16* b1 = kvs + 8192;
    __bf16* b2 = kvs + 16384;

    ATTN_STAGE(b0);   // tile 0
    ATTN_STAGE(b1);   // tile 1
#pragma unroll 1
    for (int st = 0; st < 12; st += 3) {
        AITER(b0, b2);    // compute st,   stage st+2
        AITER(b1, b0);    // compute st+1, stage st+3
        AITER(b2, b1);    // compute st+2, stage st+4
    }
    AITER(b0, b2);        // st=12, stage 14
    AITER(b1, b0);        // st=13, stage 15
    // st=14: only tile-15's 4 loads may remain in flight
    PIPE_SYNC(4);
    ATTN_STEP(b2);
    // st=15: drain
    PIPE_SYNC(0);
    ATTN_STEP(b0);

    float inv0[4], inv1[4];
#pragma unroll
    for (int r = 0; r < 4; ++r) {
        inv0[r] = 1.0f / __shfl(l_acc0, lq * 4 + r, 64);
        inv1[r] = 1.0f / __shfl(l_acc1, lq * 4 + r, 64);
    }
    __syncthreads();   // full drain+fence before reusing p_lds rows for output
#pragma unroll
    for (int j = 0; j < 4; ++j)
#pragma unroll
        for (int r = 0; r < 4; ++r) {
            p_lds[(w * 32 + lq * 4 + r) * 72 + j * 16 + lm] = (__bf16)(o_acc[0][j][r] * inv0[r]);
            p_lds[(w * 32 + 16 + lq * 4 + r) * 72 + j * 16 + lm] = (__bf16)(o_acc[1][j][r] * inv1[r]);
        }
    __syncthreads();
    __bf16* obase = attT + (size_t)b * TT * CC + (size_t)tq0 * CC + h * 64;
#pragma unroll
    for (int it = 0; it < 4; ++it) {
        int chunk = tid + 256 * it;
        int row = chunk >> 3, off = (chunk & 7) * 8;
        *(bf16x8*)&obase[(size_t)row * CC + off] = *(bf16x8*)&p_lds[row * 72 + off];
    }
}

// ---------------------------------------------------------------------------
extern "C" void kernel_launch(void* const* d_in, const int* in_sizes, int n_in,
                              void* d_out, int out_size, void* d_ws, size_t ws_size,
                              hipStream_t stream) {
    const float* x = (const float*)d_in[0];
    const float* c = (const float*)d_in[1];
    const float* Wq = (const float*)d_in[3];
    const float* bq = (const float*)d_in[4];
    const float* Wk = (const float*)d_in[5];
    const float* bk = (const float*)d_in[6];
    const float* Wv = (const float*)d_in[7];
    const float* bv = (const float*)d_in[8];
    const float* Wo = (const float*)d_in[9];
    const float* bo = (const float*)d_in[10];

    const size_t MB = 1024ull * 1024ull;
    char* ws = (char*)d_ws;
    __bf16* Wqb  = (__bf16*)(ws + 0 * MB);
    __bf16* Wkb  = (__bf16*)(ws + 2 * MB);
    __bf16* Wvb  = (__bf16*)(ws + 4 * MB);
    __bf16* Wob  = (__bf16*)(ws + 6 * MB);
    __bf16* xT   = (__bf16*)(ws + 8 * MB);
    __bf16* cT   = (__bf16*)(ws + 16 * MB);
    __bf16* qhb  = (__bf16*)(ws + 24 * MB);  // (b,h,t,d) roped+scaled
    __bf16* khb  = (__bf16*)(ws + 32 * MB);  // (b,h,t,d) roped
    __bf16* vbuf = (__bf16*)(ws + 40 * MB);  // (b,C,T)
    __bf16* attT = (__bf16*)(ws + 48 * MB);  // (b,t,c)

    prep_kernel<<<dim3(16, 16, 9), 256, 0, stream>>>(x, c, xT, cT, Wq, Wk, Wv, Wo,
                                                     Wqb, Wkb, Wvb, Wob);
    gemm_qkv_kernel<<<dim3(8, 8, 12), 256, 0, stream>>>(Wqb, Wkb, Wvb, xT, cT, bq, bk, bv,
                                                        qhb, khb, vbuf);
    attn_kernel<<<dim3(64, 8), 256, 0, stream>>>(qhb, khb, vbuf, attT);
    gemm_out_kernel<<<dim3(8, 8, 4), 256, 0, stream>>>(Wob, attT, bo, (float*)d_out);
}